// Round 1
// baseline (499.833 us; speedup 1.0000x reference)
//
#include <hip/hip_runtime.h>

// TensorProduct: N=100000 rows, MUL=64. out[row] = concat(o0[320], o1[384], o2[192]).
// All GEMMs are K=64 over {s_a, v_b[:,0..2]}; per-row nonlinearities in epilogue.
// v2: 32 rows/block, 512 threads, static per-wave job sections, weight prefetch,
//     LDS-resident sv/bias (register-pressure diet), guard-free full-tile path.

typedef __bf16 v8bf __attribute__((ext_vector_type(8)));
typedef __bf16 v4bf __attribute__((ext_vector_type(4)));
typedef float f32x4 __attribute__((ext_vector_type(4)));

#define PW0f   0.08838834764831845f   // 1/sqrt(128)
#define PW0S3f 0.05103103630798288f   // 1/sqrt(384)

// ws layout (bf16 elements), all K=64 (KS=2 k-steps of 32):
//   Wa0'  [64x320] at 0       (20480)
//   Wb1o0'[64x320] at 20480   (20480)
//   Wa1'  [64x128] at 40960   ( 8192)
//   Wb0'  [64x128] at 49152   ( 8192)
//   Wo2'  [64x 64] at 57344   ( 4096)
// frag addr: B[k][n] -> (( (n>>4)*2 + (k>>5) )*64 + ((k>>3)&3)*16 + (n&15))*8 + (k&7)

__global__ __launch_bounds__(256) void prep_weights(
    const float* __restrict__ Wa0, const float* __restrict__ Wb1o0,
    const float* __restrict__ Wa1, const float* __restrict__ Wb0,
    const float* __restrict__ Wo2, unsigned short* __restrict__ ws) {
  int t = blockIdx.x * 256 + threadIdx.x;   // grid sized to exactly 61440
  float v; int k, n, base;
  if (t < 20480) {
    k = t / 320; n = t % 320; base = 0;     v = Wa0[k * 320 + n] * PW0f;
  } else if (t < 40960) {
    int tt = t - 20480; k = tt / 320; n = tt % 320; base = 20480; v = Wb1o0[k * 320 + n] * PW0S3f;
  } else if (t < 49152) {
    int tt = t - 40960; k = tt / 128; n = tt % 128; base = 40960; v = Wa1[k * 128 + n] * PW0f;
  } else if (t < 57344) {
    int tt = t - 49152; k = tt / 128; n = tt % 128; base = 49152; v = Wb0[k * 128 + n] * PW0f;
  } else {
    int tt = t - 57344; k = tt / 64;  n = tt % 64;  base = 57344; v = Wo2[k * 64 + n] * PW0f;
  }
  int nt = n >> 4, cc = n & 15, ks = k >> 5, qq = (k >> 3) & 3, j = k & 7;
  int addr = base + ((nt * 2 + ks) * 64 + qq * 16 + cc) * 8 + j;
  __bf16 h = (__bf16)v;
  ws[addr] = __builtin_bit_cast(unsigned short, h);
}

template <bool GUARD>
__global__ __launch_bounds__(512, 4) void tp_main(
    const float* __restrict__ in1, const float* __restrict__ in2,
    const float* __restrict__ bias, const unsigned short* __restrict__ wsb,
    float* __restrict__ out, int N, int r0base) {
  // LDS: 2x 16-row A-fragment sets + per-row scalars + bias. ~17.8 KB.
  __shared__ __attribute__((aligned(16))) float s0v1[32 * 4];
  __shared__ __attribute__((aligned(16))) float biasl[320];
  __shared__ __attribute__((aligned(16))) __bf16 fsa[2][1024];      // s_a     K=64
  __shared__ __attribute__((aligned(16))) __bf16 fvb[2][3][1024];   // v_b[:,c]

  const int tid = threadIdx.x;
  const int r0 = r0base + blockIdx.x * 32;
  const int lane = tid & 63;
  const int wv = tid >> 6;    // 0..7: wave-static job section

  const unsigned short* Wa0p = wsb;
  const unsigned short* Wb1p = wsb + 20480;
  const unsigned short* Wa1p = wsb + 40960;
  const unsigned short* Wb0p = wsb + 49152;
  const unsigned short* Wo2p = wsb + 57344;

  // ---- Prefetch the first job's weight fragments BEFORE phase 1 so the
  //      L2 latency hides under the in1 load/repack (barrier blocks hoisting).
  v8bf pf0, pf1, pf2, pf3;
  if (wv < 5) {
    const int nt = wv * 4;
    pf0 = *(const v8bf*)(Wa0p + ((nt * 2 + 0) * 64 + lane) * 8);
    pf1 = *(const v8bf*)(Wa0p + ((nt * 2 + 1) * 64 + lane) * 8);
    pf2 = *(const v8bf*)(Wb1p + ((nt * 2 + 0) * 64 + lane) * 8);
    pf3 = *(const v8bf*)(Wb1p + ((nt * 2 + 1) * 64 + lane) * 8);
  } else if (wv < 7) {
    const int jt = (wv - 5) * 4;
    pf0 = *(const v8bf*)(Wa1p + ((jt * 2 + 0) * 64 + lane) * 8);
    pf1 = *(const v8bf*)(Wa1p + ((jt * 2 + 1) * 64 + lane) * 8);
    pf2 = *(const v8bf*)(Wb0p + ((jt * 2 + 0) * 64 + lane) * 8);
    pf3 = *(const v8bf*)(Wb0p + ((jt * 2 + 1) * 64 + lane) * 8);
  } else {
    pf0 = *(const v8bf*)(Wo2p + ((0 * 64 + lane)) * 8);
    pf1 = *(const v8bf*)(Wo2p + ((1 * 64 + lane)) * 8);
    pf2 = pf0; pf3 = pf1;
  }

  // ---- Phase 1: direct global->reg->LDS fragment repack (32 rows, 512 thr) ----
  {
    const int m = tid & 31;          // row within 32-row tile
    const int g = tid >> 5;          // u-group of 4: u = 4g..4g+3 (0..15)
    int rr = r0 + m; if (rr >= N) rr = N - 1;
    const float* rp = in1 + (size_t)rr * 256;
    const float4 sa4 = *(const float4*)(rp + 4 * g);
    const float4 w0  = *(const float4*)(rp + 64 + 12 * g);
    const float4 w1  = *(const float4*)(rp + 64 + 12 * g + 4);
    const float4 w2  = *(const float4*)(rp + 64 + 12 * g + 8);
    const float vf[12] = {w0.x, w0.y, w0.z, w0.w, w1.x, w1.y, w1.z, w1.w,
                          w2.x, w2.y, w2.z, w2.w};
    // A-frag slot for element (mm, k=4g+i): slot = (g>>3)*64 + ((g>>1)&3)*16 + mm,
    // j = 4*(g&1)+i.  Sub-tile set ts = m>>4.
    const int ts = m >> 4, mm = m & 15;
    const int wbase = (((g >> 3) * 64 + ((g >> 1) & 3) * 16 + mm) * 8) + 4 * (g & 1);
    v4bf pk;
    pk[0] = (__bf16)sa4.x; pk[1] = (__bf16)sa4.y; pk[2] = (__bf16)sa4.z; pk[3] = (__bf16)sa4.w;
    *(v4bf*)(&fsa[ts][wbase]) = pk;
#pragma unroll
    for (int c3 = 0; c3 < 3; ++c3) {
      pk[0] = (__bf16)vf[c3]; pk[1] = (__bf16)vf[3 + c3];
      pk[2] = (__bf16)vf[6 + c3]; pk[3] = (__bf16)vf[9 + c3];
      *(v4bf*)(&fvb[ts][c3][wbase]) = pk;
    }
    if (tid < 32) {
      int rr2 = r0 + tid; if (rr2 >= N) rr2 = N - 1;
      *(float4*)(s0v1 + tid * 4) = *(const float4*)(in2 + (size_t)rr2 * 4);
    }
    if (tid < 80) *(float4*)(biasl + tid * 4) = *(const float4*)(bias + tid * 4);
  }
  __syncthreads();

  // ---- Phase 2: static per-wave sections. Weights loaded once per job,
  //      reused for both 16-row sub-tiles. A-frags re-read from LDS (cheap),
  //      sv/bias from LDS -> small live register set, no spills at 128 cap.
  const int c = lane & 15, q = lane >> 4;

  if (wv < 5) {
    // ---- o0: tiles nt = 4*wv .. 4*wv+3 ----
#pragma unroll
    for (int j = 0; j < 4; ++j) {
      const int nt = wv * 4 + j;
      const v8bf wa0 = j ? *(const v8bf*)(Wa0p + ((nt * 2 + 0) * 64 + lane) * 8) : pf0;
      const v8bf wa1 = j ? *(const v8bf*)(Wa0p + ((nt * 2 + 1) * 64 + lane) * 8) : pf1;
      const v8bf wb0 = j ? *(const v8bf*)(Wb1p + ((nt * 2 + 0) * 64 + lane) * 8) : pf2;
      const v8bf wb1 = j ? *(const v8bf*)(Wb1p + ((nt * 2 + 1) * 64 + lane) * 8) : pf3;
      const int col = nt * 16 + c;
      const float bv = biasl[col];
#pragma unroll
      for (int t = 0; t < 2; ++t) {
        f32x4 ta = {0.f, 0.f, 0.f, 0.f};
        f32x4 tb[3]; tb[0] = ta; tb[1] = ta; tb[2] = ta;
        {
          const v8bf a0 = *(const v8bf*)(&fsa[t][(lane) * 8]);
          const v8bf a1 = *(const v8bf*)(&fsa[t][(64 + lane) * 8]);
          ta = __builtin_amdgcn_mfma_f32_16x16x32_bf16(a0, wa0, ta, 0, 0, 0);
          ta = __builtin_amdgcn_mfma_f32_16x16x32_bf16(a1, wa1, ta, 0, 0, 0);
        }
#pragma unroll
        for (int c3 = 0; c3 < 3; ++c3) {
          const v8bf b0 = *(const v8bf*)(&fvb[t][c3][(lane) * 8]);
          const v8bf b1 = *(const v8bf*)(&fvb[t][c3][(64 + lane) * 8]);
          tb[c3] = __builtin_amdgcn_mfma_f32_16x16x32_bf16(b0, wb0, tb[c3], 0, 0, 0);
          tb[c3] = __builtin_amdgcn_mfma_f32_16x16x32_bf16(b1, wb1, tb[c3], 0, 0, 0);
        }
#pragma unroll
        for (int r = 0; r < 4; ++r) {
          const int row = t * 16 + q * 4 + r;
          const int gr = r0 + row;
          const float4 s = *(const float4*)(s0v1 + row * 4);
          if (!GUARD || gr < N)
            out[(size_t)gr * 896 + col] =
                bv + s.x * ta[r] + s.y * tb[0][r] + s.z * tb[1][r] + s.w * tb[2][r];
        }
      }
    }
  } else if (wv < 7) {
    // ---- o1: tiles jt = 4*(wv-5) .. +3 ----
#pragma unroll
    for (int j = 0; j < 4; ++j) {
      const int jt = (wv - 5) * 4 + j;
      const v8bf ba0 = j ? *(const v8bf*)(Wa1p + ((jt * 2 + 0) * 64 + lane) * 8) : pf0;
      const v8bf ba1 = j ? *(const v8bf*)(Wa1p + ((jt * 2 + 1) * 64 + lane) * 8) : pf1;
      const v8bf bb0 = j ? *(const v8bf*)(Wb0p + ((jt * 2 + 0) * 64 + lane) * 8) : pf2;
      const v8bf bb1 = j ? *(const v8bf*)(Wb0p + ((jt * 2 + 1) * 64 + lane) * 8) : pf3;
#pragma unroll
      for (int t = 0; t < 2; ++t) {
        f32x4 t1 = {0.f, 0.f, 0.f, 0.f};
        f32x4 t2[3]; t2[0] = t1; t2[1] = t1; t2[2] = t1;
        {
          const v8bf a0 = *(const v8bf*)(&fsa[t][(lane) * 8]);
          const v8bf a1 = *(const v8bf*)(&fsa[t][(64 + lane) * 8]);
          t1 = __builtin_amdgcn_mfma_f32_16x16x32_bf16(a0, ba0, t1, 0, 0, 0);
          t1 = __builtin_amdgcn_mfma_f32_16x16x32_bf16(a1, ba1, t1, 0, 0, 0);
        }
#pragma unroll
        for (int c3 = 0; c3 < 3; ++c3) {
          const v8bf b0 = *(const v8bf*)(&fvb[t][c3][(lane) * 8]);
          const v8bf b1 = *(const v8bf*)(&fvb[t][c3][(64 + lane) * 8]);
          t2[c3] = __builtin_amdgcn_mfma_f32_16x16x32_bf16(b0, bb0, t2[c3], 0, 0, 0);
          t2[c3] = __builtin_amdgcn_mfma_f32_16x16x32_bf16(b1, bb1, t2[c3], 0, 0, 0);
        }
#pragma unroll
        for (int r = 0; r < 4; ++r) {
          const int row = t * 16 + q * 4 + r;
          const int gr = r0 + row;
          const float4 s = *(const float4*)(s0v1 + row * 4);
          if (!GUARD || gr < N) {
            const size_t base = (size_t)gr * 896 + 320 + 3 * (jt * 16 + c);
            out[base + 0] = t1[r] * s.y + t2[0][r] * s.x;
            out[base + 1] = t1[r] * s.z + t2[1][r] * s.x;
            out[base + 2] = t1[r] * s.w + t2[2][r] * s.x;
          }
        }
      }
    }
  } else {
    // ---- o2: tiles jt = 0..3, epilogue cross(t3, v1) ----
#pragma unroll
    for (int j = 0; j < 4; ++j) {
      const int jt = j;
      const v8bf b0v = j ? *(const v8bf*)(Wo2p + ((jt * 2 + 0) * 64 + lane) * 8) : pf0;
      const v8bf b1v = j ? *(const v8bf*)(Wo2p + ((jt * 2 + 1) * 64 + lane) * 8) : pf1;
#pragma unroll
      for (int t = 0; t < 2; ++t) {
        f32x4 t3[3];
        t3[0] = f32x4{0.f, 0.f, 0.f, 0.f}; t3[1] = t3[0]; t3[2] = t3[0];
#pragma unroll
        for (int c3 = 0; c3 < 3; ++c3) {
          const v8bf a0 = *(const v8bf*)(&fvb[t][c3][(lane) * 8]);
          const v8bf a1 = *(const v8bf*)(&fvb[t][c3][(64 + lane) * 8]);
          t3[c3] = __builtin_amdgcn_mfma_f32_16x16x32_bf16(a0, b0v, t3[c3], 0, 0, 0);
          t3[c3] = __builtin_amdgcn_mfma_f32_16x16x32_bf16(a1, b1v, t3[c3], 0, 0, 0);
        }
#pragma unroll
        for (int r = 0; r < 4; ++r) {
          const int row = t * 16 + q * 4 + r;
          const int gr = r0 + row;
          const float4 s = *(const float4*)(s0v1 + row * 4);
          if (!GUARD || gr < N) {
            const size_t base = (size_t)gr * 896 + 704 + 3 * (jt * 16 + c);
            out[base + 0] = t3[1][r] * s.w - t3[2][r] * s.z;
            out[base + 1] = t3[2][r] * s.y - t3[0][r] * s.w;
            out[base + 2] = t3[0][r] * s.z - t3[1][r] * s.y;
          }
        }
      }
    }
  }
}

extern "C" void kernel_launch(void* const* d_in, const int* in_sizes, int n_in,
                              void* d_out, int out_size, void* d_ws, size_t ws_size,
                              hipStream_t stream) {
  const float* in1   = (const float*)d_in[0];
  const float* in2   = (const float*)d_in[1];
  const float* Wa0   = (const float*)d_in[2];
  const float* Wb1o0 = (const float*)d_in[3];
  const float* Wa1   = (const float*)d_in[4];
  const float* Wb0   = (const float*)d_in[5];
  const float* Wo2   = (const float*)d_in[6];
  const float* bias  = (const float*)d_in[7];
  float* out = (float*)d_out;
  unsigned short* ws = (unsigned short*)d_ws;

  const int N = in_sizes[0] / 256;          // 100000

  hipLaunchKernelGGL(prep_weights, dim3(240), dim3(256), 0, stream,
                     Wa0, Wb1o0, Wa1, Wb0, Wo2, ws);

  const int nfull = N >> 5;                 // 3125 full 32-row tiles (N%32==0 here)
  if (nfull > 0)
    tp_main<false><<<dim3(nfull), dim3(512), 0, stream>>>(in1, in2, bias, ws, out, N, 0);
  const int rem = N & 31;
  if (rem)
    tp_main<true><<<dim3(1), dim3(512), 0, stream>>>(in1, in2, bias, ws, out, N, nfull * 32);
}

// Round 2
// 477.288 us; speedup vs baseline: 1.0472x; 1.0472x over previous
//
#include <hip/hip_runtime.h>

// TensorProduct: N=100000 rows, MUL=64. out[row] = concat(o0[320], o1[384], o2[192]).
// All GEMMs are K=64 over {s_a, v_b[:,0..2]}; per-row nonlinearities in epilogue.
// v3: v1 skeleton (16 rows/block, 256 thr, interleaved jobs) + LDS output staging:
//     all epilogue stores go to a padded LDS tile, then one fully-coalesced
//     float4 streaming write per block (every 128B line written once, fully).
//     Fixes partial-line write amplification (rows previously filled by ~32
//     scattered 64B/12B fragments over the block lifetime -> L2 evictions of
//     dirty partial lines -> HBM read-modify-write).

typedef __bf16 v8bf __attribute__((ext_vector_type(8)));
typedef __bf16 v4bf __attribute__((ext_vector_type(4)));
typedef float f32x4 __attribute__((ext_vector_type(4)));

#define PW0f   0.08838834764831845f   // 1/sqrt(128)
#define PW0S3f 0.05103103630798288f   // 1/sqrt(384)

#define STG_STRIDE 900                // 896 + 4 pad: row offset = 16 banks -> 2-way (free)

// ws layout (bf16 elements), all K=64 (KS=2 k-steps of 32):
//   Wa0'  [64x320] at 0       (20480)
//   Wb1o0'[64x320] at 20480   (20480)
//   Wa1'  [64x128] at 40960   ( 8192)
//   Wb0'  [64x128] at 49152   ( 8192)
//   Wo2'  [64x 64] at 57344   ( 4096)
// frag addr: B[k][n] -> (( (n>>4)*2 + (k>>5) )*64 + ((k>>3)&3)*16 + (n&15))*8 + (k&7)

__global__ __launch_bounds__(256) void prep_weights(
    const float* __restrict__ Wa0, const float* __restrict__ Wb1o0,
    const float* __restrict__ Wa1, const float* __restrict__ Wb0,
    const float* __restrict__ Wo2, unsigned short* __restrict__ ws) {
  int t = blockIdx.x * 256 + threadIdx.x;   // grid sized to exactly 61440
  float v; int k, n, base;
  if (t < 20480) {
    k = t / 320; n = t % 320; base = 0;     v = Wa0[k * 320 + n] * PW0f;
  } else if (t < 40960) {
    int tt = t - 20480; k = tt / 320; n = tt % 320; base = 20480; v = Wb1o0[k * 320 + n] * PW0S3f;
  } else if (t < 49152) {
    int tt = t - 40960; k = tt / 128; n = tt % 128; base = 40960; v = Wa1[k * 128 + n] * PW0f;
  } else if (t < 57344) {
    int tt = t - 49152; k = tt / 128; n = tt % 128; base = 49152; v = Wb0[k * 128 + n] * PW0f;
  } else {
    int tt = t - 57344; k = tt / 64;  n = tt % 64;  base = 57344; v = Wo2[k * 64 + n] * PW0f;
  }
  int nt = n >> 4, cc = n & 15, ks = k >> 5, qq = (k >> 3) & 3, j = k & 7;
  int addr = base + ((nt * 2 + ks) * 64 + qq * 16 + cc) * 8 + j;
  __bf16 h = (__bf16)v;
  ws[addr] = __builtin_bit_cast(unsigned short, h);
}

template <bool GUARD>
__global__ __launch_bounds__(256, 2) void tp_main(
    const float* __restrict__ in1, const float* __restrict__ in2,
    const float* __restrict__ bias, const unsigned short* __restrict__ wsb,
    float* __restrict__ out, int N) {
  // One shared buffer, two lifetimes:
  //  - phase 1 + hoist: bf16 A-fragments (fsa 2KB + fvb 3x2KB = 8KB)
  //  - phase 2 + stream: f32 staging tile [16][STG_STRIDE] = 57.6 KB
  __shared__ __attribute__((aligned(16))) char smem[16 * STG_STRIDE * 4];
  __shared__ __attribute__((aligned(16))) float s0v1[16 * 4];

  __bf16* const fsa = (__bf16*)smem;                 // [1024]
  __bf16* const fvb0 = fsa + 1024;                   // [3][1024]
  float* const stg = (float*)smem;

  const int tid = threadIdx.x;
  const int r0 = blockIdx.x * 16;

  // ---- Phase 1: direct global->reg->LDS fragment repack ----
  {
    const int m = tid & 15;          // row within tile
    const int g = tid >> 4;          // u-group of 4: u = 4g..4g+3
    int rr = r0 + m;
    if (GUARD && rr >= N) rr = N - 1;
    const float* rp = in1 + (size_t)rr * 256;
    const float4 sa4 = *(const float4*)(rp + 4 * g);
    const float4 w0  = *(const float4*)(rp + 64 + 12 * g);
    const float4 w1  = *(const float4*)(rp + 64 + 12 * g + 4);
    const float4 w2  = *(const float4*)(rp + 64 + 12 * g + 8);
    const float vf[12] = {w0.x, w0.y, w0.z, w0.w, w1.x, w1.y, w1.z, w1.w,
                          w2.x, w2.y, w2.z, w2.w};
    // A-frag slot for element (m, k=4g+i): slot = (g>>3)*64 + ((g>>1)&3)*16 + m,
    // j = 4*(g&1)+i.
    const int wbase = (((g >> 3) * 64 + ((g >> 1) & 3) * 16 + m) * 8) + 4 * (g & 1);
    v4bf pk;
    pk[0] = (__bf16)sa4.x; pk[1] = (__bf16)sa4.y; pk[2] = (__bf16)sa4.z; pk[3] = (__bf16)sa4.w;
    *(v4bf*)(fsa + wbase) = pk;
#pragma unroll
    for (int c3 = 0; c3 < 3; ++c3) {
      pk[0] = (__bf16)vf[c3]; pk[1] = (__bf16)vf[3 + c3];
      pk[2] = (__bf16)vf[6 + c3]; pk[3] = (__bf16)vf[9 + c3];
      *(v4bf*)(fvb0 + c3 * 1024 + wbase) = pk;
    }
    if (tid < 16) {
      int rr2 = r0 + tid;
      if (GUARD && rr2 >= N) rr2 = N - 1;
      *(float4*)(s0v1 + tid * 4) = *(const float4*)(in2 + (size_t)rr2 * 4);
    }
  }
  __syncthreads();

  // ---- Hoist A-fragments to registers (job-invariant), then free the LDS ----
  const int lane = tid & 63;
  const int wv = tid >> 6;
  const int c = lane & 15, q = lane >> 4;

  v8bf a_sa[2], a_vb[3][2];
#pragma unroll
  for (int ks = 0; ks < 2; ++ks) {
    a_sa[ks] = *(const v8bf*)(fsa + (ks * 64 + lane) * 8);
#pragma unroll
    for (int c3 = 0; c3 < 3; ++c3)
      a_vb[c3][ks] = *(const v8bf*)(fvb0 + c3 * 1024 + (ks * 64 + lane) * 8);
  }
  float4 sv[4];
#pragma unroll
  for (int r = 0; r < 4; ++r) sv[r] = *(const float4*)(s0v1 + (q * 4 + r) * 4);

  __syncthreads();   // frag LDS is now reusable as the staging tile

  const unsigned short* Wa0p = wsb;
  const unsigned short* Wb1p = wsb + 20480;
  const unsigned short* Wa1p = wsb + 40960;
  const unsigned short* Wb0p = wsb + 49152;
  const unsigned short* Wo2p = wsb + 57344;

  for (int job = wv; job < 32; job += 4) {
    if (job < 20) {
      // ---- o0 tile nt: 8 MFMA (K=64 x {sa, vb0, vb1, vb2}) ----
      const int nt = job;
      v8bf wa0 = *(const v8bf*)(Wa0p + ((nt * 2 + 0) * 64 + lane) * 8);
      v8bf wa1 = *(const v8bf*)(Wa0p + ((nt * 2 + 1) * 64 + lane) * 8);
      v8bf wb0 = *(const v8bf*)(Wb1p + ((nt * 2 + 0) * 64 + lane) * 8);
      v8bf wb1 = *(const v8bf*)(Wb1p + ((nt * 2 + 1) * 64 + lane) * 8);
      f32x4 ta = {0.f, 0.f, 0.f, 0.f};
      f32x4 tb[3]; tb[0] = ta; tb[1] = ta; tb[2] = ta;
      ta = __builtin_amdgcn_mfma_f32_16x16x32_bf16(a_sa[0], wa0, ta, 0, 0, 0);
      ta = __builtin_amdgcn_mfma_f32_16x16x32_bf16(a_sa[1], wa1, ta, 0, 0, 0);
#pragma unroll
      for (int c3 = 0; c3 < 3; ++c3) {
        tb[c3] = __builtin_amdgcn_mfma_f32_16x16x32_bf16(a_vb[c3][0], wb0, tb[c3], 0, 0, 0);
        tb[c3] = __builtin_amdgcn_mfma_f32_16x16x32_bf16(a_vb[c3][1], wb1, tb[c3], 0, 0, 0);
      }
      const int col = nt * 16 + c;
      const float bv = bias[col];
#pragma unroll
      for (int r = 0; r < 4; ++r)
        stg[(q * 4 + r) * STG_STRIDE + col] =
            bv + sv[r].x * ta[r] + sv[r].y * tb[0][r] + sv[r].z * tb[1][r] + sv[r].w * tb[2][r];
    } else if (job < 28) {
      // ---- o1 tile jt: t1 = sa@Wa1', t2[c] = vb[c]@Wb0' (8 MFMA) ----
      const int jt = job - 20;
      v8bf ba0 = *(const v8bf*)(Wa1p + ((jt * 2 + 0) * 64 + lane) * 8);
      v8bf ba1 = *(const v8bf*)(Wa1p + ((jt * 2 + 1) * 64 + lane) * 8);
      v8bf bb0 = *(const v8bf*)(Wb0p + ((jt * 2 + 0) * 64 + lane) * 8);
      v8bf bb1 = *(const v8bf*)(Wb0p + ((jt * 2 + 1) * 64 + lane) * 8);
      f32x4 t1 = {0.f, 0.f, 0.f, 0.f};
      f32x4 t2[3]; t2[0] = t1; t2[1] = t1; t2[2] = t1;
      t1 = __builtin_amdgcn_mfma_f32_16x16x32_bf16(a_sa[0], ba0, t1, 0, 0, 0);
      t1 = __builtin_amdgcn_mfma_f32_16x16x32_bf16(a_sa[1], ba1, t1, 0, 0, 0);
#pragma unroll
      for (int c3 = 0; c3 < 3; ++c3) {
        t2[c3] = __builtin_amdgcn_mfma_f32_16x16x32_bf16(a_vb[c3][0], bb0, t2[c3], 0, 0, 0);
        t2[c3] = __builtin_amdgcn_mfma_f32_16x16x32_bf16(a_vb[c3][1], bb1, t2[c3], 0, 0, 0);
      }
#pragma unroll
      for (int r = 0; r < 4; ++r) {
        float* sp = stg + (q * 4 + r) * STG_STRIDE + 320 + 3 * (jt * 16 + c);
        sp[0] = t1[r] * sv[r].y + t2[0][r] * sv[r].x;
        sp[1] = t1[r] * sv[r].z + t2[1][r] * sv[r].x;
        sp[2] = t1[r] * sv[r].w + t2[2][r] * sv[r].x;
      }
    } else {
      // ---- o2 tile jt: t3[c] = vb[c]@Wo2', epilogue cross(t3, v1) (6 MFMA) ----
      const int jt = job - 28;
      v8bf b0v = *(const v8bf*)(Wo2p + ((jt * 2 + 0) * 64 + lane) * 8);
      v8bf b1v = *(const v8bf*)(Wo2p + ((jt * 2 + 1) * 64 + lane) * 8);
      f32x4 t3[3];
      t3[0] = f32x4{0.f, 0.f, 0.f, 0.f}; t3[1] = t3[0]; t3[2] = t3[0];
#pragma unroll
      for (int c3 = 0; c3 < 3; ++c3) {
        t3[c3] = __builtin_amdgcn_mfma_f32_16x16x32_bf16(a_vb[c3][0], b0v, t3[c3], 0, 0, 0);
        t3[c3] = __builtin_amdgcn_mfma_f32_16x16x32_bf16(a_vb[c3][1], b1v, t3[c3], 0, 0, 0);
      }
#pragma unroll
      for (int r = 0; r < 4; ++r) {
        float* sp = stg + (q * 4 + r) * STG_STRIDE + 704 + 3 * (jt * 16 + c);
        sp[0] = t3[1][r] * sv[r].w - t3[2][r] * sv[r].z;
        sp[1] = t3[2][r] * sv[r].y - t3[0][r] * sv[r].w;
        sp[2] = t3[0][r] * sv[r].z - t3[1][r] * sv[r].y;
      }
    }
  }
  __syncthreads();

  // ---- Stream the staged tile: 16 rows x 896 f32 = 3584 float4, 14/thread.
  //      Consecutive threads -> consecutive float4 -> full 128B lines, one pass.
  {
    const float4* sp4 = (const float4*)smem;
    float4* op4 = (float4*)(out + (size_t)r0 * 896);
#pragma unroll
    for (int it = 0; it < 14; ++it) {
      const int o = tid + 256 * it;            // flat float4 index in out tile
      const int row = o / 224;                 // 224 float4 per out row
      const int c4 = o - row * 224;
      if (!GUARD || (r0 + row) < N)
        op4[o] = sp4[row * 225 + c4];          // 225 = STG_STRIDE/4
    }
  }
}

extern "C" void kernel_launch(void* const* d_in, const int* in_sizes, int n_in,
                              void* d_out, int out_size, void* d_ws, size_t ws_size,
                              hipStream_t stream) {
  const float* in1   = (const float*)d_in[0];
  const float* in2   = (const float*)d_in[1];
  const float* Wa0   = (const float*)d_in[2];
  const float* Wb1o0 = (const float*)d_in[3];
  const float* Wa1   = (const float*)d_in[4];
  const float* Wb0   = (const float*)d_in[5];
  const float* Wo2   = (const float*)d_in[6];
  const float* bias  = (const float*)d_in[7];
  float* out = (float*)d_out;
  unsigned short* ws = (unsigned short*)d_ws;

  const int N = in_sizes[0] / 256;          // 100000

  hipLaunchKernelGGL(prep_weights, dim3(240), dim3(256), 0, stream,
                     Wa0, Wb1o0, Wa1, Wb0, Wo2, ws);

  const int nfull = N >> 4;                 // 6250 full 16-row tiles (N%16==0 here)
  if (nfull > 0)
    tp_main<false><<<dim3(nfull), dim3(256), 0, stream>>>(in1, in2, bias, ws, out, nfull * 16);
  if (N & 15)
    tp_main<true><<<dim3(1), dim3(256), 0, stream>>>(in1, in2, bias, ws, out, N);
}